// Round 2
// baseline (3764.103 us; speedup 1.0000x reference)
//
#include <hip/hip_runtime.h>
#include <hip/hip_bf16.h>

// Problem constants (from reference)
#define E_N    800000
#define NODES  50000
#define NC     128     // node channels
#define EC     64      // edge channels
#define K1     320     // 2*NC + EC  (edge MLP layer-1 fan-in)
#define H1     128     // edge MLP hidden
#define O2E    64      // edge MLP out
#define NK1    192     // NC + EC    (node MLP layer-1 fan-in)

// ---------- helpers ----------
__device__ __forceinline__ float2 bfp2f(unsigned int p) {
    // packed pair: low 16 bits = bf16 of element k, high 16 = element k+1
    union { unsigned int i; float f; } lo, hi;
    lo.i = p << 16; hi.i = p & 0xffff0000u;
    float2 r; r.x = lo.f; r.y = hi.f; return r;
}
__device__ __forceinline__ unsigned short f2bf(float f) {
    union { float ff; unsigned int i; } v; v.ff = f;
    unsigned int x = v.i;
    return (unsigned short)((x + 0x7fffu + ((x >> 16) & 1u)) >> 16);
}
__device__ __forceinline__ unsigned int packbf(float a, float b) {
    return (unsigned int)f2bf(a) | ((unsigned int)f2bf(b) << 16);
}
__device__ __forceinline__ float silu_f(float x) { return x / (1.0f + __expf(-x)); }

// =====================================================================
// Edge kernel: per edge e
//   state[320] = concat(xn[snd], xn[rcv], xe[e])     (fp32, LDS)
//   h[128]     = silu(state @ eW1 + eb1)
//   o[64]      = silu(h @ eW2 + eb2)
//   out_e[e]   = o (fp32);  aggr[rcv] += o (fp32 atomics)
// Thread layout (256 threads):
//   GEMM1: thread t -> channel c1 = t&127, K-half kh1 = t>>7 (160 MACs)
//   GEMM2: thread t -> out o2 = t&63,  K-quarter kq2 = t>>6  (32 MACs)
// Weights: bf16-packed pairs in registers (fp32 activations/accum).
// =====================================================================
__global__ __launch_bounds__(256, 2) void edge_kernel(
    const float* __restrict__ xn,
    const float* __restrict__ xe,
    const int* __restrict__ ei,
    const float* __restrict__ eW1, const float* __restrict__ eb1,
    const float* __restrict__ eW2, const float* __restrict__ eb2,
    float* __restrict__ out_e,   // [E_N, 64] f32
    float* __restrict__ aggr)    // [NODES, 64] f32 (pre-zeroed)
{
    const int t   = threadIdx.x;
    const int c1  = t & 127;   // GEMM1 hidden channel
    const int kh1 = t >> 7;    // GEMM1 K-half: k in [kh1*160, +160)
    const int o2  = t & 63;    // GEMM2 output channel
    const int kq2 = t >> 6;    // GEMM2 K-quarter: k in [kq2*32, +32)

    // --- register-resident W1 slice: 160 bf16 = 80 packed dwords ---
    unsigned int w1[80];
    {
        const int k0 = kh1 * 160;
        #pragma unroll
        for (int j = 0; j < 80; ++j) {
            float lo = eW1[(size_t)(k0 + 2 * j) * H1 + c1];
            float hi = eW1[(size_t)(k0 + 2 * j + 1) * H1 + c1];
            w1[j] = packbf(lo, hi);
        }
    }
    // --- register-resident W2 slice: 32 bf16 = 16 packed dwords ---
    unsigned int w2[16];
    {
        const int k0 = kq2 * 32;
        #pragma unroll
        for (int j = 0; j < 16; ++j) {
            float lo = eW2[(size_t)(k0 + 2 * j) * O2E + o2];
            float hi = eW2[(size_t)(k0 + 2 * j + 1) * O2E + o2];
            w2[j] = packbf(lo, hi);
        }
    }
    const float b1  = eb1[c1];
    const float b2v = eb2[o2];

    __shared__ float4 sbuf4[K1 / 4];  // state, 320 f32
    __shared__ float  red1[H1];       // GEMM1 partial reduce
    __shared__ float2 hbuf[H1 / 2];   // hidden, 128 f32
    __shared__ float  red2[3 * O2E];  // GEMM2 partial reduce

    for (int e = blockIdx.x; e < E_N; e += gridDim.x) {
        const int snd = ei[e];
        const int rcv = ei[E_N + e];

        // ---- stage state into LDS (float4 vector loads) ----
        {
            const float4* s_row = (const float4*)(xn + (size_t)snd * NC);  // 32 float4
            const float4* r_row = (const float4*)(xn + (size_t)rcv * NC);  // 32 float4
            const float4* e_row = (const float4*)(xe + (size_t)e * EC);    // 16 float4
            if (t < 32)       sbuf4[t]      = s_row[t];        // k   0..127
            else if (t < 64)  sbuf4[t]      = r_row[t - 32];   // k 128..255
            else if (t < 80)  sbuf4[t]      = e_row[t - 64];   // k 256..319
        }
        __syncthreads();

        // ---- GEMM1: 160 MACs/thread, bf16 W in regs, f32 state from LDS ----
        float acc = 0.f;
        {
            const float2* sp = ((const float2*)sbuf4) + kh1 * 80;
            #pragma unroll
            for (int j = 0; j < 80; ++j) {
                float2 wv = bfp2f(w1[j]);
                float2 sv = sp[j];
                acc += wv.x * sv.x;
                acc += wv.y * sv.y;
            }
        }
        if (kh1 == 1) red1[c1] = acc;
        __syncthreads();
        if (kh1 == 0) {
            float h = silu_f(acc + red1[c1] + b1);
            ((float*)hbuf)[c1] = h;
        }
        __syncthreads();

        // ---- GEMM2: 32 MACs/thread ----
        float acc2 = 0.f;
        {
            const float2* hp = hbuf + kq2 * 16;
            #pragma unroll
            for (int j = 0; j < 16; ++j) {
                float2 wv = bfp2f(w2[j]);
                float2 hv = hp[j];
                acc2 += wv.x * hv.x;
                acc2 += wv.y * hv.y;
            }
        }
        if (kq2 > 0) red2[(kq2 - 1) * O2E + o2] = acc2;
        __syncthreads();
        if (kq2 == 0) {
            float o = acc2 + red2[o2] + red2[O2E + o2] + red2[2 * O2E + o2] + b2v;
            o = silu_f(o);
            out_e[(size_t)e * O2E + o2] = o;
            unsafeAtomicAdd(&aggr[(size_t)rcv * O2E + o2], o);
        }
        __syncthreads();  // protect LDS before next iteration's staging
    }
}

// =====================================================================
// Node kernel: per node v
//   n[192]   = concat(xn[v], aggr[v])
//   h[128]   = silu(n @ nW1 + nb1)
//   out[128] = h @ nW2 + nb2          (no final silu)
// Thread layout: c = t&127, kh = t>>7.
// =====================================================================
__global__ __launch_bounds__(256, 2) void node_kernel(
    const float* __restrict__ xn,
    const float* __restrict__ aggr,
    const float* __restrict__ nW1, const float* __restrict__ nb1,
    const float* __restrict__ nW2, const float* __restrict__ nb2,
    float* __restrict__ out_n)   // [NODES, 128] f32
{
    const int t  = threadIdx.x;
    const int c  = t & 127;
    const int kh = t >> 7;   // 0/1

    // W1 slice: k in [kh*96, +96) -> 48 packed dwords
    unsigned int w1[48];
    {
        const int k0 = kh * 96;
        #pragma unroll
        for (int j = 0; j < 48; ++j) {
            float lo = nW1[(size_t)(k0 + 2 * j) * NC + c];
            float hi = nW1[(size_t)(k0 + 2 * j + 1) * NC + c];
            w1[j] = packbf(lo, hi);
        }
    }
    // W2 slice: k in [kh*64, +64) -> 32 packed dwords
    unsigned int w2[32];
    {
        const int k0 = kh * 64;
        #pragma unroll
        for (int j = 0; j < 32; ++j) {
            float lo = nW2[(size_t)(k0 + 2 * j) * NC + c];
            float hi = nW2[(size_t)(k0 + 2 * j + 1) * NC + c];
            w2[j] = packbf(lo, hi);
        }
    }
    const float b1 = nb1[c];
    const float b2 = nb2[c];

    __shared__ float4 sbuf4[NK1 / 4];  // 192 f32
    __shared__ float  red1[NC];
    __shared__ float2 hbuf[NC / 2];    // 128 f32

    for (int v = blockIdx.x; v < NODES; v += gridDim.x) {
        // ---- stage: xn row (128 f32) + aggr row (64 f32) ----
        {
            const float4* n_row = (const float4*)(xn + (size_t)v * NC);    // 32 float4
            const float4* a_row = (const float4*)(aggr + (size_t)v * EC);  // 16 float4
            if (t < 32)       sbuf4[t] = n_row[t];        // k   0..127
            else if (t < 48)  sbuf4[t] = a_row[t - 32];   // k 128..191
        }
        __syncthreads();

        // ---- GEMM1: 96 MACs/thread ----
        float acc = 0.f;
        {
            const float2* sp = ((const float2*)sbuf4) + kh * 48;
            #pragma unroll
            for (int j = 0; j < 48; ++j) {
                float2 wv = bfp2f(w1[j]);
                float2 sv = sp[j];
                acc += wv.x * sv.x;
                acc += wv.y * sv.y;
            }
        }
        if (kh == 1) red1[c] = acc;
        __syncthreads();
        if (kh == 0) {
            float h = silu_f(acc + red1[c] + b1);
            ((float*)hbuf)[c] = h;
        }
        __syncthreads();

        // ---- GEMM2: 64 MACs/thread ----
        float acc2 = 0.f;
        {
            const float2* hp = hbuf + kh * 32;
            #pragma unroll
            for (int j = 0; j < 32; ++j) {
                float2 wv = bfp2f(w2[j]);
                float2 hv = hp[j];
                acc2 += wv.x * hv.x;
                acc2 += wv.y * hv.y;
            }
        }
        if (kh == 1) red1[c] = acc2;   // reuse safe: last read was before prev barrier
        __syncthreads();
        if (kh == 0) {
            float o = acc2 + red1[c] + b2;
            out_n[(size_t)v * NC + c] = o;
        }
        __syncthreads();
    }
}

extern "C" void kernel_launch(void* const* d_in, const int* in_sizes, int n_in,
                              void* d_out, int out_size, void* d_ws, size_t ws_size,
                              hipStream_t stream) {
    const float* xn  = (const float*)d_in[0];   // [50000,128] f32
    const float* xe  = (const float*)d_in[1];   // [800000,64] f32
    const int*   ei  = (const int*)d_in[2];     // [2,800000] int32
    const float* eW1 = (const float*)d_in[3];   // [320,128]
    const float* eb1 = (const float*)d_in[4];   // [128]
    const float* eW2 = (const float*)d_in[5];   // [128,64]
    const float* eb2 = (const float*)d_in[6];   // [64]
    const float* nW1 = (const float*)d_in[7];   // [192,128]
    const float* nb1 = (const float*)d_in[8];   // [128]
    const float* nW2 = (const float*)d_in[9];   // [128,128]
    const float* nb2 = (const float*)d_in[10];  // [128]

    float* out_n = (float*)d_out;               // [50000,128] f32
    float* out_e = out_n + (size_t)NODES * NC;  // [800000,64] f32
    float* aggr  = (float*)d_ws;                // [50000,64] f32

    // zero the scatter accumulator (ws is re-poisoned before every launch)
    hipMemsetAsync(aggr, 0, (size_t)NODES * O2E * sizeof(float), stream);

    hipLaunchKernelGGL(edge_kernel, dim3(1024), dim3(256), 0, stream,
                       xn, xe, ei, eW1, eb1, eW2, eb2, out_e, aggr);
    hipLaunchKernelGGL(node_kernel, dim3(1024), dim3(256), 0, stream,
                       xn, aggr, nW1, nb1, nW2, nb2, out_n);
}